// Round 3
// baseline (131075.952 us; speedup 1.0000x reference)
//
#include <hip/hip_runtime.h>
#include <hip/hip_bf16.h>

// B=32, T=2048, I=H=512, L=4. Output = stacked final cell states c_n (L,B,H).
// Fused persistent kernel: 4 layers pipelined across 256 WGs (1/CU), per-step
// device-scope counting barriers per (layer, batch-group); h flows through an
// 8-slot bf16 ring in ws. Input dtype (f32 vs bf16) detected at runtime from
// x's bit patterns; both template variants launch, the mismatched one exits.
#define BATCH   32
#define SEQT    2048
#define HDIM    512
#define LAYERS  4
#define RINGW   8
#define NTHR    256

typedef short short8 __attribute__((ext_vector_type(8)));   // 8 bf16 (4 VGPRs)
typedef float f32x4  __attribute__((ext_vector_type(4)));
typedef unsigned int uint4v __attribute__((ext_vector_type(4)));
typedef unsigned short ushort;

__device__ __forceinline__ float bf2f(ushort u) {
    return __uint_as_float(((unsigned int)u) << 16);
}
__device__ __forceinline__ ushort f2bf(float f) {
    unsigned int u = __float_as_uint(f);
    u = (u + 0x7FFF + ((u >> 16) & 1)) >> 16;   // RNE
    return (ushort)u;
}
__device__ __forceinline__ float sigmoid_fast(float x) {
    return 1.0f / (1.0f + __expf(-x));
}
__device__ __forceinline__ float tanh_fast(float x) {
    return 1.0f - 2.0f / (__expf(2.0f * x) + 1.0f);  // saturates at +-1
}

template <typename T> struct IO;
template <> struct IO<ushort> {            // bf16 tensors
    static constexpr int IS_F32 = 0;
    static __device__ __forceinline__ float  ld (const ushort* p) { return bf2f(*p); }
    static __device__ __forceinline__ short8 ld8(const ushort* p) { return *(const short8*)p; }
    static __device__ __forceinline__ void   st (ushort* p, float v) { *p = f2bf(v); }
};
template <> struct IO<float> {             // f32 tensors (converted to bf16 on load)
    static constexpr int IS_F32 = 1;
    static __device__ __forceinline__ float  ld (const float* p) { return *p; }
    static __device__ __forceinline__ short8 ld8(const float* p) {
        short8 r;
        #pragma unroll
        for (int i = 0; i < 8; ++i) r[i] = (short)f2bf(p[i]);
        return r;
    }
    static __device__ __forceinline__ void   st (float* p, float v) { *p = v; }
};

__global__ void zero_ints_kernel(int* p) { p[threadIdx.x] = 0; }

__global__ void zero_ring_kernel(uint4v* r) {
    r[blockIdx.x * 256 + threadIdx.x] = (uint4v){0, 0, 0, 0};
}

// Dtype detector: bf16 N(0,1) data has biased exponent <= ~130; f32 data's low
// half-words are uniform random bits -> some exponent >= 0xC0 w.p. ~1.
__global__ void detect_kernel(const ushort* x, int* flag) {
    int bad = 0;
    for (int i = threadIdx.x; i < 4096; i += 256)
        if (((x[i] >> 7) & 0xFF) >= 0xC0) bad = 1;
    if (bad)
        __hip_atomic_fetch_or(flag, 1, __ATOMIC_RELEASE, __HIP_MEMORY_SCOPE_AGENT);
}

__device__ __forceinline__ void spin_ge(int* p, int target) {
    while (__hip_atomic_load(p, __ATOMIC_ACQUIRE, __HIP_MEMORY_SCOPE_AGENT) < target)
        __builtin_amdgcn_s_sleep(1);
}

template <typename T>
__global__ __launch_bounds__(NTHR, 2) void lstm_fused_kernel(
    const T* __restrict__ x,      // (B,T,512)
    const T* __restrict__ h0,     // (L,B,H)
    const T* __restrict__ c0,     // (L,B,H)
    const T* __restrict__ wih,    // (L,4H,512)
    const T* __restrict__ whh,    // (L,4H,512)
    const T* __restrict__ bih,    // (L,4H)
    const T* __restrict__ bhh,    // (L,4H)
    T*       __restrict__ c_out,  // (L,B,H) = d_out
    ushort*               ring,   // [LAYERS][RINGW][BATCH][HDIM] bf16 (1 MiB)
    int*                  cnt)    // [0..7] step counters, [15] dtype flag
{
    // dtype gate: only the matching variant runs
    {
        int fl = __hip_atomic_load(&cnt[15], __ATOMIC_ACQUIRE, __HIP_MEMORY_SCOPE_AGENT);
        if ((fl != 0) != (IO<T>::IS_F32 != 0)) return;
    }

    const int tid   = threadIdx.x;
    const int wg    = blockIdx.x;
    const int l     = wg >> 6;          // layer 0..3
    const int ug    = wg & 31;          // unit group: units [ug*16, ug*16+16)
    const int bg    = (wg >> 5) & 1;    // batch group: batches [bg*16, bg*16+16)
    const int wave  = tid >> 6;
    const int lane  = tid & 63;
    const int lquad = lane >> 4;
    const int l15   = lane & 15;

    // partial gate accumulators: [wave][col=gate*16+unit][batch-row, padded to 20]
    __shared__ float pg[4][64][20];

    // ---- resident B fragments: lane n=l15 holds W[n][k], k = kbase+it*32+lquad*8+j
    // waves 0,1: Wih k-halves [0,256),[256,512); waves 2,3: Whh halves.
    short8 bf[4][8];
    {
        const T* wsrc = (wave < 2) ? (wih + (size_t)l * 4 * HDIM * HDIM)
                                   : (whh + (size_t)l * 4 * HDIM * HDIM);
        const int kbase = (wave & 1) * 256;
        const int unit  = ug * 16 + l15;
        #pragma unroll
        for (int sub = 0; sub < 4; ++sub) {           // gate (i,f,g,o)
            const T* rp = wsrc + (size_t)(sub * HDIM + unit) * HDIM + kbase + lquad * 8;
            #pragma unroll
            for (int it = 0; it < 8; ++it)
                bf[sub][it] = IO<T>::ld8(rp + it * 32);
        }
    }

    // ---- per-thread recurrent state (epilogue mapping: 256 thr <-> 16b x 16u)
    const int eb = tid >> 4;
    const int eu = tid & 15;
    const int gb = bg * 16 + eb;
    const int gu = ug * 16 + eu;
    float c_state = IO<T>::ld(c0 + (size_t)l * BATCH * HDIM + gb * HDIM + gu);
    float bias[4];
    #pragma unroll
    for (int g = 0; g < 4; ++g)
        bias[g] = IO<T>::ld(bih + l * 4 * HDIM + g * HDIM + gu) +
                  IO<T>::ld(bhh + l * 4 * HDIM + g * HDIM + gu);

    const int ab = bg * 16 + l15;       // A-frag batch row (m = lane&15)
    int* c_own  = &cnt[l * 2 + bg];
    int* c_prod = (l > 0) ? &cnt[(l - 1) * 2 + bg] : nullptr;
    int* c_cons = (l < LAYERS - 1) ? &cnt[(l + 1) * 2 + bg] : nullptr;

    for (int t = 0; t < SEQT; ++t) {
        // ---- wait: producer done step t; own group done t-1; ring backpressure
        if (tid == 0) {
            if (c_prod)               spin_ge(c_prod, 32 * (t + 1));
            if (t > 0)                spin_ge(c_own,  32 * t);
            if (c_cons && t >= RINGW) spin_ge(c_cons, 32 * (t - RINGW + 1));
        }
        __syncthreads();
        __threadfence();   // acquire: invalidate stale cached ring data

        f32x4 acc[4];
        #pragma unroll
        for (int sub = 0; sub < 4; ++sub) acc[sub] = (f32x4){0.f, 0.f, 0.f, 0.f};

        // A-frag source: external tensor (T) or internal ring (bf16)
        const T*      aT = nullptr;
        const ushort* aR = nullptr;
        if (wave < 2) {
            if (l == 0)
                aT = x + ((size_t)ab * SEQT + t) * HDIM + wave * 256 + lquad * 8;
            else
                aR = ring + (((size_t)(l - 1) * RINGW + (t & (RINGW - 1))) * BATCH + ab) * HDIM
                     + wave * 256 + lquad * 8;
        } else {
            if (t == 0)
                aT = h0 + (size_t)l * BATCH * HDIM + (size_t)ab * HDIM
                     + (wave - 2) * 256 + lquad * 8;
            else
                aR = ring + (((size_t)l * RINGW + ((t - 1) & (RINGW - 1))) * BATCH + ab) * HDIM
                     + (wave - 2) * 256 + lquad * 8;
        }

        #pragma unroll
        for (int it = 0; it < 8; ++it) {
            short8 av = aT ? IO<T>::ld8(aT + it * 32)
                           : *(const short8*)(aR + it * 32);
            #pragma unroll
            for (int sub = 0; sub < 4; ++sub)
                acc[sub] = __builtin_amdgcn_mfma_f32_16x16x32_bf16(av, bf[sub][it], acc[sub], 0, 0, 0);
        }

        // D layout (m89): col = lane&15, row = quad*4 + reg
        #pragma unroll
        for (int sub = 0; sub < 4; ++sub)
            *(f32x4*)&pg[wave][sub * 16 + l15][lquad * 4] = acc[sub];
        __syncthreads();

        // ---- epilogue: reduce 4 wave-partials, activations, state update
        float gs[4];
        #pragma unroll
        for (int g = 0; g < 4; ++g) {
            float s = bias[g];
            #pragma unroll
            for (int w = 0; w < 4; ++w) s += pg[w][g * 16 + eu][eb];
            gs[g] = s;
        }
        float ig = sigmoid_fast(gs[0]);
        float fg = sigmoid_fast(gs[1]);
        float gg = tanh_fast(gs[2]);
        float og = sigmoid_fast(gs[3]);
        c_state = fg * c_state + ig * gg;
        float hv = og * tanh_fast(c_state);

        ring[(((size_t)l * RINGW + (t & (RINGW - 1))) * BATCH + gb) * HDIM + gu] = f2bf(hv);
        if (t == SEQT - 1)
            IO<T>::st(c_out + (size_t)l * BATCH * HDIM + gb * HDIM + gu, c_state);

        // ---- publish step t
        __threadfence();   // release: drain h stores to device-coherent point
        __syncthreads();   // all threads' stores done, all pg reads done
        if (tid == 0)
            __hip_atomic_fetch_add(c_own, 1, __ATOMIC_RELEASE, __HIP_MEMORY_SCOPE_AGENT);
    }
}

extern "C" void kernel_launch(void* const* d_in, const int* in_sizes, int n_in,
                              void* d_out, int out_size, void* d_ws, size_t ws_size,
                              hipStream_t stream) {
    (void)in_sizes; (void)n_in; (void)out_size; (void)ws_size;

    // ws layout: [0,64) = 16 counters (incl. dtype flag at [15]); [1024, +1MiB) = h ring
    int*    cnt  = (int*)d_ws;
    ushort* ring = (ushort*)((char*)d_ws + 1024);

    zero_ints_kernel<<<1, 16, 0, stream>>>(cnt);
    zero_ring_kernel<<<256, 256, 0, stream>>>((uint4v*)ring);
    detect_kernel<<<1, 256, 0, stream>>>((const ushort*)d_in[0], &cnt[15]);

    lstm_fused_kernel<ushort><<<LAYERS * 64, NTHR, 0, stream>>>(
        (const ushort*)d_in[0], (const ushort*)d_in[1], (const ushort*)d_in[2],
        (const ushort*)d_in[3], (const ushort*)d_in[4], (const ushort*)d_in[5],
        (const ushort*)d_in[6], (ushort*)d_out, ring, cnt);

    lstm_fused_kernel<float><<<LAYERS * 64, NTHR, 0, stream>>>(
        (const float*)d_in[0], (const float*)d_in[1], (const float*)d_in[2],
        (const float*)d_in[3], (const float*)d_in[4], (const float*)d_in[5],
        (const float*)d_in[6], (float*)d_out, ring, cnt);
}

// Round 4
// 17677.478 us; speedup vs baseline: 7.4149x; 7.4149x over previous
//
#include <hip/hip_runtime.h>
#include <hip/hip_bf16.h>

// B=32, T=2048, I=H=512, L=4. Output = stacked final cell states c_n (L,B,H).
// Fused persistent kernel: 4 layers pipelined across 256 WGs (1 per CU).
// Weights VGPR-resident; h flows through an 8-slot bf16 ring in ws.
// Sync: per-(layer,batch-group) counting barriers, per-access coherent
// (sc0/sc1 write-through atomics) — NO agent fences / buffer_wbl2 in the loop.
#define BATCH   32
#define SEQT    2048
#define HDIM    512
#define LAYERS  4
#define RINGW   8
#define NTHR    256

typedef short short8 __attribute__((ext_vector_type(8)));   // 8 bf16 (4 VGPRs)
typedef float f32x4  __attribute__((ext_vector_type(4)));
typedef unsigned int uint4v __attribute__((ext_vector_type(4)));
typedef unsigned short ushort;
typedef unsigned long long u64;

__device__ __forceinline__ float bf2f(ushort u) {
    return __uint_as_float(((unsigned int)u) << 16);
}
__device__ __forceinline__ ushort f2bf(float f) {
    unsigned int u = __float_as_uint(f);
    u = (u + 0x7FFF + ((u >> 16) & 1)) >> 16;   // RNE
    return (ushort)u;
}
__device__ __forceinline__ float sigmoid_fast(float x) {
    return 1.0f / (1.0f + __expf(-x));
}
__device__ __forceinline__ float tanh_fast(float x) {
    return 1.0f - 2.0f / (__expf(2.0f * x) + 1.0f);  // saturates at +-1
}

// Coherent (agent-scope, per-access) ring accessors — no cache-wide ops.
__device__ __forceinline__ short8 ring_ld16(const ushort* p) {   // p 16B-aligned
    u64 a = __hip_atomic_load((const u64*)p,       __ATOMIC_RELAXED, __HIP_MEMORY_SCOPE_AGENT);
    u64 b = __hip_atomic_load((const u64*)(p + 4), __ATOMIC_RELAXED, __HIP_MEMORY_SCOPE_AGENT);
    union { u64 q[2]; short8 s; } u; u.q[0] = a; u.q[1] = b; return u.s;
}

template <typename T> struct IO;
template <> struct IO<ushort> {            // bf16 tensors
    static constexpr int IS_F32 = 0;
    static __device__ __forceinline__ float  ld (const ushort* p) { return bf2f(*p); }
    static __device__ __forceinline__ short8 ld8(const ushort* p) { return *(const short8*)p; }
    static __device__ __forceinline__ void   st (ushort* p, float v) { *p = f2bf(v); }
};
template <> struct IO<float> {             // f32 tensors (converted to bf16 on load)
    static constexpr int IS_F32 = 1;
    static __device__ __forceinline__ float  ld (const float* p) { return *p; }
    static __device__ __forceinline__ short8 ld8(const float* p) {
        short8 r;
        #pragma unroll
        for (int i = 0; i < 8; ++i) r[i] = (short)f2bf(p[i]);
        return r;
    }
    static __device__ __forceinline__ void   st (float* p, float v) { *p = v; }
};

__global__ void zero_ints_kernel(int* p) { p[threadIdx.x] = 0; }

__global__ void zero_ring_kernel(uint4v* r) {
    r[blockIdx.x * 256 + threadIdx.x] = (uint4v){0, 0, 0, 0};
}

// Dtype detector: bf16 N(0,1) data has biased exponent <= ~130; f32 data's low
// half-words are uniform random bits -> some exponent >= 0xC0 w.p. ~1.
__global__ void detect_kernel(const ushort* x, int* flag) {
    int bad = 0;
    for (int i = threadIdx.x; i < 4096; i += 256)
        if (((x[i] >> 7) & 0xFF) >= 0xC0) bad = 1;
    if (bad)
        __hip_atomic_fetch_or(flag, 1, __ATOMIC_RELEASE, __HIP_MEMORY_SCOPE_AGENT);
}

// RELAXED spin: coherent load at IF, no buffer_inv per poll.
__device__ __forceinline__ void spin_ge(int* p, int target) {
    while (__hip_atomic_load(p, __ATOMIC_RELAXED, __HIP_MEMORY_SCOPE_AGENT) < target)
        __builtin_amdgcn_s_sleep(1);
}

#define CPAD 32   // ints per counter slot (128 B): one cache line each

template <typename T>
__global__ __launch_bounds__(NTHR, 2) void lstm_fused_kernel(
    const T* __restrict__ x,      // (B,T,512)
    const T* __restrict__ h0,     // (L,B,H)
    const T* __restrict__ c0,     // (L,B,H)
    const T* __restrict__ wih,    // (L,4H,512)
    const T* __restrict__ whh,    // (L,4H,512)
    const T* __restrict__ bih,    // (L,4H)
    const T* __restrict__ bhh,    // (L,4H)
    T*       __restrict__ c_out,  // (L,B,H) = d_out
    ushort*               ring,   // [LAYERS][RINGW][BATCH][HDIM] bf16 (1 MiB)
    int*                  cnt)    // padded counters; dtype flag at cnt[512]
{
    // dtype gate: only the matching variant runs
    {
        int fl = __hip_atomic_load(&cnt[512], __ATOMIC_ACQUIRE, __HIP_MEMORY_SCOPE_AGENT);
        if ((fl != 0) != (IO<T>::IS_F32 != 0)) return;
    }

    const int tid   = threadIdx.x;
    const int wg    = blockIdx.x;
    const int l     = wg >> 6;          // layer 0..3
    const int ug    = wg & 31;          // unit group: units [ug*16, ug*16+16)
    const int bg    = (wg >> 5) & 1;    // batch group: batches [bg*16, bg*16+16)
    const int wave  = tid >> 6;
    const int lane  = tid & 63;
    const int lquad = lane >> 4;
    const int l15   = lane & 15;

    // partial gate accumulators: [wave][col=gate*16+unit][batch-row, padded to 20]
    __shared__ float pg[4][64][20];

    // ---- resident B fragments: lane n=l15 holds W[n][k], k = kbase+it*32+lquad*8+j
    // waves 0,1: Wih k-halves [0,256),[256,512); waves 2,3: Whh halves.
    short8 bf[4][8];
    {
        const T* wsrc = (wave < 2) ? (wih + (size_t)l * 4 * HDIM * HDIM)
                                   : (whh + (size_t)l * 4 * HDIM * HDIM);
        const int kbase = (wave & 1) * 256;
        const int unit  = ug * 16 + l15;
        #pragma unroll
        for (int sub = 0; sub < 4; ++sub) {           // gate (i,f,g,o)
            const T* rp = wsrc + (size_t)(sub * HDIM + unit) * HDIM + kbase + lquad * 8;
            #pragma unroll
            for (int it = 0; it < 8; ++it)
                bf[sub][it] = IO<T>::ld8(rp + it * 32);
        }
    }

    // ---- per-thread recurrent state (epilogue mapping: 256 thr <-> 16b x 16u)
    const int eb = tid >> 4;
    const int eu = tid & 15;
    const int gb = bg * 16 + eb;
    const int gu = ug * 16 + eu;
    float c_state = IO<T>::ld(c0 + (size_t)l * BATCH * HDIM + gb * HDIM + gu);
    float bias[4];
    #pragma unroll
    for (int g = 0; g < 4; ++g)
        bias[g] = IO<T>::ld(bih + l * 4 * HDIM + g * HDIM + gu) +
                  IO<T>::ld(bhh + l * 4 * HDIM + g * HDIM + gu);

    const int ab = bg * 16 + l15;       // A-frag batch row (m = lane&15)
    int* c_own  = cnt + (l * 2 + bg) * CPAD;
    int* c_prod = (l > 0) ? (cnt + ((l - 1) * 2 + bg) * CPAD) : nullptr;
    int* c_cons = (l < LAYERS - 1) ? (cnt + ((l + 1) * 2 + bg) * CPAD) : nullptr;

    for (int t = 0; t < SEQT; ++t) {
        // ---- wait: producer done step t; own group done t-1; ring backpressure
        if (tid == 0) {
            if (c_prod)               spin_ge(c_prod, 32 * (t + 1));
            if (t > 0)                spin_ge(c_own,  32 * t);
            if (c_cons && t >= RINGW) spin_ge(c_cons, 32 * (t - RINGW + 1));
        }
        __syncthreads();   // broadcast barrier pass; orders ring loads after spin

        f32x4 acc[4];
        #pragma unroll
        for (int sub = 0; sub < 4; ++sub) acc[sub] = (f32x4){0.f, 0.f, 0.f, 0.f};

        // A-frag source: external tensor (plain cached loads) or ring (coherent)
        const T*      aT = nullptr;
        const ushort* aR = nullptr;
        if (wave < 2) {
            if (l == 0)
                aT = x + ((size_t)ab * SEQT + t) * HDIM + wave * 256 + lquad * 8;
            else
                aR = ring + (((size_t)(l - 1) * RINGW + (t & (RINGW - 1))) * BATCH + ab) * HDIM
                     + wave * 256 + lquad * 8;
        } else {
            if (t == 0)
                aT = h0 + (size_t)l * BATCH * HDIM + (size_t)ab * HDIM
                     + (wave - 2) * 256 + lquad * 8;
            else
                aR = ring + (((size_t)l * RINGW + ((t - 1) & (RINGW - 1))) * BATCH + ab) * HDIM
                     + (wave - 2) * 256 + lquad * 8;
        }

        #pragma unroll
        for (int it = 0; it < 8; ++it) {
            short8 av = aT ? IO<T>::ld8(aT + it * 32) : ring_ld16(aR + it * 32);
            #pragma unroll
            for (int sub = 0; sub < 4; ++sub)
                acc[sub] = __builtin_amdgcn_mfma_f32_16x16x32_bf16(av, bf[sub][it], acc[sub], 0, 0, 0);
        }

        // D layout (m89): col = lane&15, row = quad*4 + reg
        #pragma unroll
        for (int sub = 0; sub < 4; ++sub)
            *(f32x4*)&pg[wave][sub * 16 + l15][lquad * 4] = acc[sub];
        __syncthreads();

        // ---- epilogue: reduce 4 wave-partials, activations, state update
        float gs[4];
        #pragma unroll
        for (int g = 0; g < 4; ++g) {
            float s = bias[g];
            #pragma unroll
            for (int w = 0; w < 4; ++w) s += pg[w][g * 16 + eu][eb];
            gs[g] = s;
        }
        float ig = sigmoid_fast(gs[0]);
        float fg = sigmoid_fast(gs[1]);
        float gg = tanh_fast(gs[2]);
        float og = sigmoid_fast(gs[3]);
        c_state = fg * c_state + ig * gg;
        float hv = og * tanh_fast(c_state);

        // ---- write-through h store: pack 2 bf16 (units gu, gu+1) per uint
        {
            unsigned int hb = f2bf(hv);
            unsigned int pa = (unsigned int)__shfl_xor((int)hb, 1);  // partner unit
            if ((eu & 1) == 0) {
                unsigned int val = hb | (pa << 16);
                ushort* dst = ring + (((size_t)l * RINGW + (t & (RINGW - 1))) * BATCH + gb) * HDIM + gu;
                __hip_atomic_store((unsigned int*)dst, val, __ATOMIC_RELAXED, __HIP_MEMORY_SCOPE_AGENT);
            }
        }
        if (t == SEQT - 1)
            IO<T>::st(c_out + (size_t)l * BATCH * HDIM + gb * HDIM + gu, c_state);

        // ---- publish step t: vmcnt drain (no cache ops) + relaxed add
        __threadfence_block();   // s_waitcnt only: write-through stores performed
        __syncthreads();         // all threads' stores done, all pg reads done
        if (tid == 0)
            __hip_atomic_fetch_add(c_own, 1, __ATOMIC_RELAXED, __HIP_MEMORY_SCOPE_AGENT);
    }
}

extern "C" void kernel_launch(void* const* d_in, const int* in_sizes, int n_in,
                              void* d_out, int out_size, void* d_ws, size_t ws_size,
                              hipStream_t stream) {
    (void)in_sizes; (void)n_in; (void)out_size; (void)ws_size;

    // ws layout: [0,4096) counters (8 x 128B padded + dtype flag at int 512);
    //            [8192, +1MiB) h ring
    int*    cnt  = (int*)d_ws;
    ushort* ring = (ushort*)((char*)d_ws + 8192);

    zero_ints_kernel<<<1, 1024, 0, stream>>>(cnt);
    zero_ring_kernel<<<256, 256, 0, stream>>>((uint4v*)ring);
    detect_kernel<<<1, 256, 0, stream>>>((const ushort*)d_in[0], &cnt[512]);

    lstm_fused_kernel<ushort><<<LAYERS * 64, NTHR, 0, stream>>>(
        (const ushort*)d_in[0], (const ushort*)d_in[1], (const ushort*)d_in[2],
        (const ushort*)d_in[3], (const ushort*)d_in[4], (const ushort*)d_in[5],
        (const ushort*)d_in[6], (ushort*)d_out, ring, cnt);

    lstm_fused_kernel<float><<<LAYERS * 64, NTHR, 0, stream>>>(
        (const float*)d_in[0], (const float*)d_in[1], (const float*)d_in[2],
        (const float*)d_in[3], (const float*)d_in[4], (const float*)d_in[5],
        (const float*)d_in[6], (float*)d_out, ring, cnt);
}

// Round 5
// 8974.077 us; speedup vs baseline: 14.6061x; 1.9698x over previous
//
#include <hip/hip_runtime.h>
#include <hip/hip_bf16.h>

// B=32, T=2048, I=H=512, L=4. Output = stacked final cell states c_n (L,B,H).
// Fused persistent kernel: 4 layers pipelined across 256 WGs (1 per CU).
// Weights VGPR/AGPR-resident. Synchronization is DATAFLOW: each h element is
// stored as a self-validating 32-bit word (tag<<16 | bf16), consumers poll the
// data directly with sc0/sc1 coherent loads. Counters are only a rare
// backpressure guard (every CHK steps, with slack). No fences in the loop.
#define BATCH   32
#define SEQT    2048
#define HDIM    512
#define LAYERS  4
#define RINGW   8         // ring slots per layer
#define CHK     4         // backpressure check period
#define NTHR    256

typedef short short8 __attribute__((ext_vector_type(8)));   // 8 bf16 (4 VGPRs)
typedef float f32x4  __attribute__((ext_vector_type(4)));
typedef unsigned int uint4v __attribute__((ext_vector_type(4)));
typedef unsigned short ushort;
typedef unsigned int uint;

__device__ __forceinline__ float bf2f(ushort u) {
    return __uint_as_float(((uint)u) << 16);
}
__device__ __forceinline__ ushort f2bf(float f) {
    uint u = __float_as_uint(f);
    u = (u + 0x7FFF + ((u >> 16) & 1)) >> 16;   // RNE
    return (ushort)u;
}
__device__ __forceinline__ float sigmoid_fast(float x) {
    return 1.0f / (1.0f + __expf(-x));
}
__device__ __forceinline__ float tanh_fast(float x) {
    return 1.0f - 2.0f / (__expf(2.0f * x) + 1.0f);  // saturates at +-1
}

// Single coherent dword load (probe): bypasses L1/L2, reads at IF.
__device__ __forceinline__ uint coh_ld32(const uint* p) {
    uint r;
    asm volatile("global_load_dword %0, %1, off sc0 sc1\n\ts_waitcnt vmcnt(0)"
                 : "=v"(r) : "v"(p) : "memory");
    return r;
}

// Bulk coherent fragment load: 16x dwordx4 in flight, ONE latency.
// Layout per lane: base p; chunk (it, half) at byte offset it*128 + half*16.
__device__ __forceinline__ void coh_bulk16(const uint* p,
    uint4v& a0, uint4v& a1, uint4v& a2,  uint4v& a3,
    uint4v& a4, uint4v& a5, uint4v& a6,  uint4v& a7,
    uint4v& a8, uint4v& a9, uint4v& a10, uint4v& a11,
    uint4v& a12, uint4v& a13, uint4v& a14, uint4v& a15) {
    asm volatile(
        "global_load_dwordx4 %0, %16, off sc0 sc1\n\t"
        "global_load_dwordx4 %1, %16, off offset:16 sc0 sc1\n\t"
        "global_load_dwordx4 %2, %16, off offset:128 sc0 sc1\n\t"
        "global_load_dwordx4 %3, %16, off offset:144 sc0 sc1\n\t"
        "global_load_dwordx4 %4, %16, off offset:256 sc0 sc1\n\t"
        "global_load_dwordx4 %5, %16, off offset:272 sc0 sc1\n\t"
        "global_load_dwordx4 %6, %16, off offset:384 sc0 sc1\n\t"
        "global_load_dwordx4 %7, %16, off offset:400 sc0 sc1\n\t"
        "global_load_dwordx4 %8, %16, off offset:512 sc0 sc1\n\t"
        "global_load_dwordx4 %9, %16, off offset:528 sc0 sc1\n\t"
        "global_load_dwordx4 %10, %16, off offset:640 sc0 sc1\n\t"
        "global_load_dwordx4 %11, %16, off offset:656 sc0 sc1\n\t"
        "global_load_dwordx4 %12, %16, off offset:768 sc0 sc1\n\t"
        "global_load_dwordx4 %13, %16, off offset:784 sc0 sc1\n\t"
        "global_load_dwordx4 %14, %16, off offset:896 sc0 sc1\n\t"
        "global_load_dwordx4 %15, %16, off offset:912 sc0 sc1\n\t"
        "s_waitcnt vmcnt(0)"
        : "=&v"(a0), "=&v"(a1), "=&v"(a2), "=&v"(a3),
          "=&v"(a4), "=&v"(a5), "=&v"(a6), "=&v"(a7),
          "=&v"(a8), "=&v"(a9), "=&v"(a10), "=&v"(a11),
          "=&v"(a12), "=&v"(a13), "=&v"(a14), "=&v"(a15)
        : "v"(p) : "memory");
}

template <typename T> struct IO;
template <> struct IO<ushort> {            // bf16 tensors
    static constexpr int IS_F32 = 0;
    static __device__ __forceinline__ float  ld (const ushort* p) { return bf2f(*p); }
    static __device__ __forceinline__ short8 ld8(const ushort* p) { return *(const short8*)p; }
    static __device__ __forceinline__ void   st (ushort* p, float v) { *p = f2bf(v); }
};
template <> struct IO<float> {             // f32 tensors (converted to bf16 on load)
    static constexpr int IS_F32 = 1;
    static __device__ __forceinline__ float  ld (const float* p) { return *p; }
    static __device__ __forceinline__ short8 ld8(const float* p) {
        short8 r;
        #pragma unroll
        for (int i = 0; i < 8; ++i) r[i] = (short)f2bf(p[i]);
        return r;
    }
    static __device__ __forceinline__ void   st (float* p, float v) { *p = v; }
};

__global__ void zero_ints_kernel(int* p) { p[threadIdx.x] = 0; }

__global__ void zero_ring_kernel(uint4v* r) {
    r[blockIdx.x * 256 + threadIdx.x] = (uint4v){0, 0, 0, 0};
}

// Dtype detector: bf16 N(0,1) never has biased exponent >= 0xC0; f32 low
// half-words are ~uniform random -> some hit w.p. ~1.
__global__ void detect_kernel(const ushort* x, int* flag) {
    int bad = 0;
    for (int i = threadIdx.x; i < 4096; i += 256)
        if (((x[i] >> 7) & 0xFF) >= 0xC0) bad = 1;
    if (bad)
        __hip_atomic_fetch_or(flag, 1, __ATOMIC_RELEASE, __HIP_MEMORY_SCOPE_AGENT);
}

__device__ __forceinline__ void spin_ge(int* p, int target) {
    while (__hip_atomic_load(p, __ATOMIC_RELAXED, __HIP_MEMORY_SCOPE_AGENT) < target)
        __builtin_amdgcn_s_sleep(1);
}

#define CPAD 32   // ints per counter slot (128 B line each)

template <typename T>
__global__ __launch_bounds__(NTHR, 1) void lstm_fused_kernel(
    const T* __restrict__ x,      // (B,T,512)
    const T* __restrict__ h0,     // (L,B,H)
    const T* __restrict__ c0,     // (L,B,H)
    const T* __restrict__ wih,    // (L,4H,512)
    const T* __restrict__ whh,    // (L,4H,512)
    const T* __restrict__ bih,    // (L,4H)
    const T* __restrict__ bhh,    // (L,4H)
    T*       __restrict__ c_out,  // (L,B,H) = d_out
    uint*                 ring,   // [LAYERS][RINGW][BATCH][HDIM] uint (2 MiB)
    int*                  cnt)    // padded step counters; dtype flag at cnt[512]
{
    {   // dtype gate: only the matching variant runs
        int fl = __hip_atomic_load(&cnt[512], __ATOMIC_ACQUIRE, __HIP_MEMORY_SCOPE_AGENT);
        if ((fl != 0) != (IO<T>::IS_F32 != 0)) return;
    }

    const int tid   = threadIdx.x;
    const int wg    = blockIdx.x;
    const int l     = wg >> 6;          // layer 0..3
    const int ug    = wg & 31;          // unit group: units [ug*16, ug*16+16)
    const int bg    = (wg >> 5) & 1;    // batch group: batches [bg*16, bg*16+16)
    const int wave  = tid >> 6;
    const int lane  = tid & 63;
    const int lquad = lane >> 4;
    const int l15   = lane & 15;

    __shared__ float pg[4][64][20];     // [wave][gate*16+unit][batch, pad 20]

    // ---- resident B fragments: lane n=l15 holds W[n][k], k = kbase+it*32+lquad*8+j
    short8 bf[4][8];
    {
        const T* wsrc = (wave < 2) ? (wih + (size_t)l * 4 * HDIM * HDIM)
                                   : (whh + (size_t)l * 4 * HDIM * HDIM);
        const int kbase = (wave & 1) * 256;
        const int unit  = ug * 16 + l15;
        #pragma unroll
        for (int sub = 0; sub < 4; ++sub) {
            const T* rp = wsrc + (size_t)(sub * HDIM + unit) * HDIM + kbase + lquad * 8;
            #pragma unroll
            for (int it = 0; it < 8; ++it)
                bf[sub][it] = IO<T>::ld8(rp + it * 32);
        }
    }

    // ---- per-thread recurrent state (epilogue mapping: 256 thr <-> 16b x 16u)
    const int eb = tid >> 4;
    const int eu = tid & 15;
    const int gb = bg * 16 + eb;
    const int gu = ug * 16 + eu;
    float c_state = IO<T>::ld(c0 + (size_t)l * BATCH * HDIM + gb * HDIM + gu);
    float bias[4];
    #pragma unroll
    for (int g = 0; g < 4; ++g)
        bias[g] = IO<T>::ld(bih + l * 4 * HDIM + g * HDIM + gu) +
                  IO<T>::ld(bhh + l * 4 * HDIM + g * HDIM + gu);

    const int ab = bg * 16 + l15;       // A-frag batch row (m = lane&15)
    int* c_own  = cnt + (l * 2 + bg) * CPAD;
    int* c_cons = (l < LAYERS - 1) ? (cnt + ((l + 1) * 2 + bg) * CPAD) : nullptr;

    for (int t = 0; t < SEQT; ++t) {
        // ---- rare backpressure guard (overwrite safety for ring slot reuse).
        // Writes at steps u in [t, t+CHK) overwrite step u-RINGW data, read by
        // own peers at u-RINGW+1 and by consumer layer at u-RINGW. Worst case
        // u = t+CHK-1: own >= 32*(t-3), cons >= 32*(t-4)  (RINGW=8, CHK=4).
        if (tid == 0 && (t & (CHK - 1)) == 0 && t >= CHK) {
            int tg = 32 * (t - 3);
            if (tg > 0) spin_ge(c_own, tg);
            if (c_cons) {
                int tg2 = 32 * (t - 4);
                if (tg2 > 0) spin_ge(c_cons, tg2);
            }
        }

        // ---- acquire A fragments (dataflow-synced via tags)
        short8 av[8];
        const T*    aT = nullptr;
        const uint* aP = nullptr;
        uint want = 0;
        if (wave < 2) {
            if (l == 0)
                aT = x + ((size_t)ab * SEQT + t) * HDIM + wave * 256 + lquad * 8;
            else {
                want = (uint)((t + 1) & 0xFFFF);  // producer step t
                aP = ring + (((size_t)(l - 1) * RINGW + (t & (RINGW - 1))) * BATCH + ab) * HDIM
                     + wave * 256 + lquad * 8;
            }
        } else {
            if (t == 0)
                aT = h0 + (size_t)l * BATCH * HDIM + (size_t)ab * HDIM
                     + (wave - 2) * 256 + lquad * 8;
            else {
                want = (uint)(t & 0xFFFF);        // own step t-1
                aP = ring + (((size_t)l * RINGW + ((t - 1) & (RINGW - 1))) * BATCH + ab) * HDIM
                     + (wave - 2) * 256 + lquad * 8;
            }
        }

        if (aT) {
            #pragma unroll
            for (int it = 0; it < 8; ++it) av[it] = IO<T>::ld8(aT + it * 32);
        } else {
            // sparse probe: one word per lane (the last-arriving chunk)
            while (!__all((coh_ld32(aP + 228) >> 16) == want))
                __builtin_amdgcn_s_sleep(1);
            // bulk load + full validate (retry on partial publish)
            uint4v w0,w1,w2,w3,w4,w5,w6,w7,w8,w9,w10,w11,w12,w13,w14,w15;
            uint4v wantv = (uint4v){want, want, want, want};
            for (;;) {
                coh_bulk16(aP, w0,w1,w2,w3,w4,w5,w6,w7,w8,w9,w10,w11,w12,w13,w14,w15);
                uint4v b4 = ((w0 >> 16) ^ wantv) | ((w1 >> 16) ^ wantv)
                          | ((w2 >> 16) ^ wantv) | ((w3 >> 16) ^ wantv)
                          | ((w4 >> 16) ^ wantv) | ((w5 >> 16) ^ wantv)
                          | ((w6 >> 16) ^ wantv) | ((w7 >> 16) ^ wantv)
                          | ((w8 >> 16) ^ wantv) | ((w9 >> 16) ^ wantv)
                          | ((w10 >> 16) ^ wantv) | ((w11 >> 16) ^ wantv)
                          | ((w12 >> 16) ^ wantv) | ((w13 >> 16) ^ wantv)
                          | ((w14 >> 16) ^ wantv) | ((w15 >> 16) ^ wantv);
                uint bad = b4[0] | b4[1] | b4[2] | b4[3];
                if (__all(bad == 0)) break;
                __builtin_amdgcn_s_sleep(1);
            }
            #define RPK(IT, WA, WB) { short8 v_;                               \
                v_[0]=(short)WA[0]; v_[1]=(short)WA[1];                        \
                v_[2]=(short)WA[2]; v_[3]=(short)WA[3];                        \
                v_[4]=(short)WB[0]; v_[5]=(short)WB[1];                        \
                v_[6]=(short)WB[2]; v_[7]=(short)WB[3]; av[IT]=v_; }
            RPK(0, w0,  w1)  RPK(1, w2,  w3)  RPK(2, w4,  w5)  RPK(3, w6,  w7)
            RPK(4, w8,  w9)  RPK(5, w10, w11) RPK(6, w12, w13) RPK(7, w14, w15)
            #undef RPK
        }

        f32x4 acc[4];
        #pragma unroll
        for (int sub = 0; sub < 4; ++sub) acc[sub] = (f32x4){0.f, 0.f, 0.f, 0.f};
        #pragma unroll
        for (int it = 0; it < 8; ++it) {
            #pragma unroll
            for (int sub = 0; sub < 4; ++sub)
                acc[sub] = __builtin_amdgcn_mfma_f32_16x16x32_bf16(av[it], bf[sub][it], acc[sub], 0, 0, 0);
        }

        // D layout (m89): col = lane&15, row = quad*4 + reg
        #pragma unroll
        for (int sub = 0; sub < 4; ++sub)
            *(f32x4*)&pg[wave][sub * 16 + l15][lquad * 4] = acc[sub];
        __syncthreads();

        // ---- epilogue
        float gs[4];
        #pragma unroll
        for (int g = 0; g < 4; ++g) {
            float s = bias[g];
            #pragma unroll
            for (int w = 0; w < 4; ++w) s += pg[w][g * 16 + eu][eb];
            gs[g] = s;
        }
        float ig = sigmoid_fast(gs[0]);
        float fg = sigmoid_fast(gs[1]);
        float gg = tanh_fast(gs[2]);
        float og = sigmoid_fast(gs[3]);
        c_state = fg * c_state + ig * gg;
        float hv = og * tanh_fast(c_state);

        // self-validating h word: tag(t+1) | bf16(h)
        {
            uint val = ((uint)((t + 1) & 0xFFFF) << 16) | (uint)f2bf(hv);
            uint* dst = ring + (((size_t)l * RINGW + (t & (RINGW - 1))) * BATCH + gb) * HDIM + gu;
            __hip_atomic_store(dst, val, __ATOMIC_RELAXED, __HIP_MEMORY_SCOPE_AGENT);
        }
        if (t == SEQT - 1)
            IO<T>::st(c_out + (size_t)l * BATCH * HDIM + gb * HDIM + gu, c_state);

        __syncthreads();   // pg reads done before next step's writes; orders cnt add
        if (tid == 0)      // step-completion count (backpressure only)
            __hip_atomic_fetch_add(c_own, 1, __ATOMIC_RELAXED, __HIP_MEMORY_SCOPE_AGENT);
    }
}

extern "C" void kernel_launch(void* const* d_in, const int* in_sizes, int n_in,
                              void* d_out, int out_size, void* d_ws, size_t ws_size,
                              hipStream_t stream) {
    (void)in_sizes; (void)n_in; (void)out_size; (void)ws_size;

    // ws: [0,4096) counters + dtype flag (int 512); [8192, +2MiB) tagged h ring
    int*  cnt  = (int*)d_ws;
    uint* ring = (uint*)((char*)d_ws + 8192);

    zero_ints_kernel<<<1, 1024, 0, stream>>>(cnt);
    zero_ring_kernel<<<512, 256, 0, stream>>>((uint4v*)ring);   // 2 MiB
    detect_kernel<<<1, 256, 0, stream>>>((const ushort*)d_in[0], &cnt[512]);

    lstm_fused_kernel<ushort><<<LAYERS * 64, NTHR, 0, stream>>>(
        (const ushort*)d_in[0], (const ushort*)d_in[1], (const ushort*)d_in[2],
        (const ushort*)d_in[3], (const ushort*)d_in[4], (const ushort*)d_in[5],
        (const ushort*)d_in[6], (ushort*)d_out, ring, cnt);

    lstm_fused_kernel<float><<<LAYERS * 64, NTHR, 0, stream>>>(
        (const float*)d_in[0], (const float*)d_in[1], (const float*)d_in[2],
        (const float*)d_in[3], (const float*)d_in[4], (const float*)d_in[5],
        (const float*)d_in[6], (float*)d_out, ring, cnt);
}